// Round 10
// baseline (174.644 us; speedup 1.0000x reference)
//
#include <hip/hip_runtime.h>

// Two-phase EdgeNetwork, atomic-free hot path, operand-swapped MFMA.
//   Phase A (k_transform): T[e] = (bond[e]@K + bias).reshape(32,32) @ atom[nbr[e]]
//     as C^T = W^T @ P^T on mfma_f32_16x16x32_f16:
//       A-operand = W fragments (A[i][k] = W[k][i], 68 VGPRs, same packing as R5)
//       B-operand = P fragments (P[e][s*32+j] = bond[e,s]*nb[e,j], s=16 -> bias)
//     C layout: col = edge, row = output-col -> each lane stores 4 consecutive
//     output cols of one edge as ONE 8B f16 store (coalesced, no atomics).
//     Also does the bucket-place phase (cnt/slots) before its main loop.
//   Phase B (k_reduce): out[a] = sum of T rows listed in slots[a] (64B/edge).

typedef _Float16 half8 __attribute__((ext_vector_type(8)));
typedef _Float16 half4t __attribute__((ext_vector_type(4)));
typedef float float4v __attribute__((ext_vector_type(4)));

constexpr int NA = 100000;
constexpr int E  = 400000;
constexpr int TILES = E / 32;      // 12500
constexpr int NBLK  = 768;         // transform grid (3 blocks/CU)
constexpr int NWAVES = NBLK * 4;   // 3072 waves
constexpr int HALFW  = NWAVES / 2; // 1536 tile-streams (2 col-half waves/tile)
constexpr int MAXDEG = 32;         // P(Poisson(4) > 32) ~ 1e-19 per atom

// ws layout: cnt | slots | T  = 0.5 + 12.8 + 25.6 MB = 38.9 MB (R4-proven size)
constexpr size_t OFF_CNT   = 0;
constexpr size_t OFF_SLOTS = 512 * 1024;
constexpr size_t OFF_T     = OFF_SLOTS + (size_t)NA * MAXDEG * 4;

__global__ void k_zero(int* __restrict__ cnt) {
  int i = blockIdx.x * blockDim.x + threadIdx.x;
  if (i < NA) cnt[i] = 0;
}

static __device__ inline half8 cvt8(float4 a, float4 b) {
  half8 r = { (_Float16)a.x, (_Float16)a.y, (_Float16)a.z, (_Float16)a.w,
              (_Float16)b.x, (_Float16)b.y, (_Float16)b.z, (_Float16)b.w };
  return r;
}

static __device__ inline half8 splat8(_Float16 v) {
  half8 r = {v, v, v, v, v, v, v, v};
  return r;
}

__global__ __launch_bounds__(256, 3)
void k_transform(const float* __restrict__ atom,
                 const float* __restrict__ bondf,
                 const int* __restrict__ pairs,
                 const float* __restrict__ Kmat,
                 const float* __restrict__ bias,
                 int* __restrict__ cnt,
                 int* __restrict__ slots,
                 _Float16* __restrict__ T)
{
  const int2* pairs2 = (const int2*)pairs;

  // ---- Bucket-place phase (consumed by k_reduce, next dispatch).
  for (int e = blockIdx.x * 256 + threadIdx.x; e < E; e += NBLK * 256) {
    const int s = pairs2[e].x;
    int p = atomicAdd(&cnt[s], 1);
    if (p < MAXDEG) slots[s * MAXDEG + p] = e;
  }

  const int tid  = threadIdx.x;
  const int lane = tid & 63;
  const int wid  = blockIdx.x * 4 + (tid >> 6);
  const int h    = wid & 1;          // column half this wave owns
  const int q    = lane >> 4;
  const int el   = lane & 15;
  const int n    = el + h * 16;
  const int j0   = q * 8;

  // A-operand fragments of W^T for all 17 K-steps (same packing as before):
  // Wr[s][j] = W[s*32 + q*8 + j][el + 16h]
  half8 Wr[17];
  #pragma unroll
  for (int s = 0; s < 17; ++s) {
    const float* src = (s < 16) ? (Kmat + s * 1024 + n * 32 + j0)
                                : (bias + n * 32 + j0);
    half8 w;
    #pragma unroll
    for (int j = 0; j < 8; ++j) w[j] = (_Float16)src[j];
    Wr[s] = w;
  }

  const int start  = wid >> 1;
  const int stride = HALFW;

  auto ldpv = [&](int t) -> int2 {
    const int tc = t < TILES ? t : TILES - 1;   // clamp: loads stay valid
    int2 v = make_int2(0, 0);
    if (lane < 32) v = pairs2[tc * 32 + lane];
    return v;
  };

  if (start >= TILES) return;

  // ---- Pipeline prologue: stage tile `start`, indices for start+stride.
  int2 pv0 = ldpv(start);
  int2 pv1 = ldpv(start + stride);

  half8 nbA_c, nbB_c, bA0_c, bA1_c, bB0_c, bB1_c;
  {
    const int aA = __shfl(pv0.y, el);
    const int aB = __shfl(pv0.y, el + 16);
    const float4* pa = (const float4*)(atom + (size_t)aA * 32 + j0);
    const float4* pb = (const float4*)(atom + (size_t)aB * 32 + j0);
    nbA_c = cvt8(pa[0], pa[1]);
    nbB_c = cvt8(pb[0], pb[1]);
    const float4* ra = (const float4*)(bondf + (size_t)(start * 32 + el) * 16);
    const float4* rb = (const float4*)(bondf + (size_t)(start * 32 + el + 16) * 16);
    bA0_c = cvt8(ra[0], ra[1]);  bA1_c = cvt8(ra[2], ra[3]);
    bB0_c = cvt8(rb[0], rb[1]);  bB1_c = cvt8(rb[2], rb[3]);
  }

  for (int t = start; t < TILES; t += stride) {
    const int tn = t + stride;

    // ---- Stage next tile (gathers in flight over this tile's compute).
    half8 nbA_n, nbB_n, bA0_n, bA1_n, bB0_n, bB1_n;
    {
      const int aA = __shfl(pv1.y, el);
      const int aB = __shfl(pv1.y, el + 16);
      const float4* pa = (const float4*)(atom + (size_t)aA * 32 + j0);
      const float4* pb = (const float4*)(atom + (size_t)aB * 32 + j0);
      nbA_n = cvt8(pa[0], pa[1]);
      nbB_n = cvt8(pb[0], pb[1]);
      const int tc = tn < TILES ? tn : TILES - 1;
      const float4* ra = (const float4*)(bondf + (size_t)(tc * 32 + el) * 16);
      const float4* rb = (const float4*)(bondf + (size_t)(tc * 32 + el + 16) * 16);
      bA0_n = cvt8(ra[0], ra[1]);  bA1_n = cvt8(ra[2], ra[3]);
      bB0_n = cvt8(rb[0], rb[1]);  bB1_n = cvt8(rb[2], rb[3]);
    }
    const int2 pv2 = ldpv(tn + stride);

    // ---- Compute current tile: A = Wr (W^T), B = P-fragments.
    float4v acc0 = {0.f, 0.f, 0.f, 0.f};
    float4v acc1 = {0.f, 0.f, 0.f, 0.f};
    #pragma unroll
    for (int s = 0; s < 16; ++s) {
      const _Float16 sA = (s < 8) ? bA0_c[s] : bA1_c[s - 8];
      const _Float16 sB = (s < 8) ? bB0_c[s] : bB1_c[s - 8];
      const half8 aAf = nbA_c * splat8(sA);
      const half8 aBf = nbB_c * splat8(sB);
      acc0 = __builtin_amdgcn_mfma_f32_16x16x32_f16(Wr[s], aAf, acc0, 0, 0, 0);
      acc1 = __builtin_amdgcn_mfma_f32_16x16x32_f16(Wr[s], aBf, acc1, 0, 0, 0);
    }
    acc0 = __builtin_amdgcn_mfma_f32_16x16x32_f16(Wr[16], nbA_c, acc0, 0, 0, 0);
    acc1 = __builtin_amdgcn_mfma_f32_16x16x32_f16(Wr[16], nbB_c, acc1, 0, 0, 0);

    // ---- Epilogue: C col = edge el, C rows = output cols q*4+r (+16h).
    // One 8B f16 store per edge per lane. Coalesced, no atomics.
    {
      const int e0 = t * 32 + el;
      half4t h0 = { (_Float16)acc0[0], (_Float16)acc0[1],
                    (_Float16)acc0[2], (_Float16)acc0[3] };
      *(half4t*)(T + (size_t)e0 * 32 + h * 16 + q * 4) = h0;
      const int e1 = e0 + 16;
      half4t h1 = { (_Float16)acc1[0], (_Float16)acc1[1],
                    (_Float16)acc1[2], (_Float16)acc1[3] };
      *(half4t*)(T + (size_t)e1 * 32 + h * 16 + q * 4) = h1;
    }

    // ---- Rotate pipeline registers.
    pv0 = pv1; pv1 = pv2;
    nbA_c = nbA_n; nbB_c = nbB_n;
    bA0_c = bA0_n; bA1_c = bA1_n; bB0_c = bB0_n; bB1_c = bB1_n;
  }
}

__global__ __launch_bounds__(256)
void k_reduce(const int* __restrict__ cnt, const int* __restrict__ slots,
              const _Float16* __restrict__ T, float* __restrict__ out) {
  const int tidg = blockIdx.x * 256 + threadIdx.x;
  const int a = tidg >> 5;          // atom
  const int c = tidg & 31;          // column
  if (a >= NA) return;
  const int d = min(cnt[a], MAXDEG);
  const int* row = slots + (size_t)a * MAXDEG;
  float sum = 0.f;
  for (int p = 0; p < d; ++p) {
    const int e = row[p];                      // uniform across 32 col-lanes
    sum += (float)T[(size_t)e * 32 + c];       // 64B contiguous per edge
  }
  out[(size_t)a * 32 + c] = sum;
}

extern "C" void kernel_launch(void* const* d_in, const int* in_sizes, int n_in,
                              void* d_out, int out_size, void* d_ws, size_t ws_size,
                              hipStream_t stream) {
  const float* atom  = (const float*)d_in[0];   // (100000, 32) f32
  const float* bondf = (const float*)d_in[1];   // (400000, 16) f32
  const int*   pairs = (const int*)d_in[2];     // (400000, 2) int32
  const float* Kmat  = (const float*)d_in[3];   // (16, 1024) f32
  const float* bias  = (const float*)d_in[4];   // (1024,) f32
  float* out = (float*)d_out;                   // (100000, 32) f32

  int*      cnt   = (int*)((char*)d_ws + OFF_CNT);
  int*      slots = (int*)((char*)d_ws + OFF_SLOTS);
  _Float16* T     = (_Float16*)((char*)d_ws + OFF_T);

  k_zero<<<(NA + 255) / 256, 256, 0, stream>>>(cnt);
  k_transform<<<NBLK, 256, 0, stream>>>(atom, bondf, pairs, Kmat, bias,
                                        cnt, slots, T);
  k_reduce<<<(NA * 32 + 255) / 256, 256, 0, stream>>>(cnt, slots, T, out);
}